// Round 6
// baseline (218.965 us; speedup 1.0000x reference)
//
#include <hip/hip_runtime.h>

// NCC loss, fused single-kernel, v2 (vectorized-LDS).
// Inputs y_true, y_pred: (2,1,160,192,160) FP32. Output: 1 FP32 scalar = -sum(cc).
// R5 diagnosis: LDS-instruction-bound (45 b32 H-taps + 27 b32 W-taps per thread
// per slice ~= 146us model vs 132us measured). v2 vectorizes all LDS traffic:
// b128 staging, register W-slide (products computed once), b128 H-taps.
#define ND 2
#define DD 160
#define HH 192
#define WW 160
#define HW (HH * WW)

constexpr int TW    = 16;          // output tile width
constexpr int TH    = 16;          // output tile height
constexpr int WLO   = TW + 8;      // 24 raw cols incl. halo
constexpr int HLO   = TH + 8;      // 24 raw rows incl. halo
constexpr int CHUNK = 40;          // output d's per block
constexpr int NCH   = DD / CHUNK;  // 4
constexpr int NSL   = CHUNK + 8;   // 48 slices per block

__global__ __launch_bounds__(256)
void ncc_fused(const float* __restrict__ I, const float* __restrict__ J,
               float* __restrict__ outp)
{
    __shared__ float  rawI[HLO][WLO];      // 2.3 KB
    __shared__ float  rawJ[HLO][WLO];      // 2.3 KB
    __shared__ float4 sws[HLO][TW];        // products 0-3 (I,J,II,JJ), 6 KB
    __shared__ float  sw4[HLO][TW];        // product 4 (IJ), 1.5 KB
    __shared__ float  wred[4];

    const int tid  = threadIdx.x;
    const int w0   = blockIdx.x * TW;
    const int h0   = blockIdx.y * TH;
    const int z    = blockIdx.z;            // n * NCH + chunk
    const int n    = z / NCH;
    const int d0   = (z % NCH) * CHUNK;
    const int lane = tid & 63;
    const int wid  = tid >> 6;
    const int oh   = tid >> 4;              // this thread's output pixel
    const int ow   = tid & 15;

    float rbuf[5][9];
    #pragma unroll
    for (int p = 0; p < 5; ++p)
        #pragma unroll
        for (int q = 0; q < 9; ++q) rbuf[p][q] = 0.f;
    float run0 = 0.f, run1 = 0.f, run2 = 0.f, run3 = 0.f, run4 = 0.f;
    float acc = 0.f;
    const float inv = 1.0f / 729.0f;

    #pragma unroll 1
    for (int g = 0; g < 6; ++g) {           // 6 x 9 = 54 >= NSL
        #pragma unroll
        for (int jj = 0; jj < 9; ++jj) {
            const int s = g * 9 + jj;       // uniform across block
            if (s < NSL) {
                const int dd  = d0 - 4 + s; // slice entering the window
                const bool dok = (dd >= 0) && (dd < DD);
                const int slice = (n * DD + dd) * HW;

                // ---- stage 1: raw tile -> LDS, float4 wide ----
                // 288 jobs: arr(2) x row(24) x chunk(6); W-chunks are either
                // fully inside [0,W) or fully outside (W % 4 == 0, w0 % 16 == 0).
                for (int idx = tid; idx < 2 * HLO * 6; idx += 256) {
                    const int arr = idx / (HLO * 6);
                    const int r   = idx - arr * (HLO * 6);
                    const int row = r / 6;
                    const int ch  = r - row * 6;
                    const int gh  = h0 + row - 4;
                    const int gws = w0 + ch * 4 - 4;
                    float4 v = make_float4(0.f, 0.f, 0.f, 0.f);
                    if (dok && gh >= 0 && gh < HH && gws >= 0 && gws < WW) {
                        const float* src = arr ? J : I;
                        v = *(const float4*)(src + slice + gh * WW + gws);
                    }
                    float* dst = (arr ? &rawJ[0][0] : &rawI[0][0]) + row * WLO + ch * 4;
                    *(float4*)dst = v;
                }
                __syncthreads();

                // ---- stage 2: register W-slide, 48 jobs (12 lanes/wave) ----
                if (lane < 12) {
                    const int j    = wid * 12 + lane;   // 0..47
                    const int row  = j >> 1;            // 0..23
                    const int runb = (j & 1) * 8;       // output w base (0 or 8)
                    float aI[16], aJ[16];
                    #pragma unroll
                    for (int q = 0; q < 4; ++q) {
                        *(float4*)&aI[q * 4] = *(const float4*)&rawI[row][runb + q * 4];
                        *(float4*)&aJ[q * 4] = *(const float4*)&rawJ[row][runb + q * 4];
                    }
                    // output w = runb+t uses raw floats [t .. t+8]
                    float x[16];
                    // product IJ first (short liveness, scattered b32 writes)
                    #pragma unroll
                    for (int i = 0; i < 16; ++i) x[i] = aI[i] * aJ[i];
                    {
                        float sa = x[0]+x[1]+x[2]+x[3]+x[4]+x[5]+x[6]+x[7]+x[8];
                        sw4[row][runb] = sa;
                        #pragma unroll
                        for (int t = 1; t < 8; ++t) {
                            sa += x[t + 8] - x[t - 1];
                            sw4[row][runb + t] = sa;
                        }
                    }
                    float S0[8], S1[8], S2[8], S3[8];
                    #pragma unroll
                    for (int i = 0; i < 16; ++i) x[i] = aI[i];
                    {
                        float sa = x[0]+x[1]+x[2]+x[3]+x[4]+x[5]+x[6]+x[7]+x[8];
                        S0[0] = sa;
                        #pragma unroll
                        for (int t = 1; t < 8; ++t) { sa += x[t+8] - x[t-1]; S0[t] = sa; }
                    }
                    #pragma unroll
                    for (int i = 0; i < 16; ++i) x[i] = aJ[i];
                    {
                        float sa = x[0]+x[1]+x[2]+x[3]+x[4]+x[5]+x[6]+x[7]+x[8];
                        S1[0] = sa;
                        #pragma unroll
                        for (int t = 1; t < 8; ++t) { sa += x[t+8] - x[t-1]; S1[t] = sa; }
                    }
                    #pragma unroll
                    for (int i = 0; i < 16; ++i) x[i] = aI[i] * aI[i];
                    {
                        float sa = x[0]+x[1]+x[2]+x[3]+x[4]+x[5]+x[6]+x[7]+x[8];
                        S2[0] = sa;
                        #pragma unroll
                        for (int t = 1; t < 8; ++t) { sa += x[t+8] - x[t-1]; S2[t] = sa; }
                    }
                    #pragma unroll
                    for (int i = 0; i < 16; ++i) x[i] = aJ[i] * aJ[i];
                    {
                        float sa = x[0]+x[1]+x[2]+x[3]+x[4]+x[5]+x[6]+x[7]+x[8];
                        S3[0] = sa;
                        #pragma unroll
                        for (int t = 1; t < 8; ++t) { sa += x[t+8] - x[t-1]; S3[t] = sa; }
                    }
                    #pragma unroll
                    for (int t = 0; t < 8; ++t)
                        sws[row][runb + t] = make_float4(S0[t], S1[t], S2[t], S3[t]);
                }
                __syncthreads();

                // ---- stage 3: 9-tap H-sum (b128 + b32), D-ring, cc ----
                float t0 = 0.f, t1 = 0.f, t2 = 0.f, t3 = 0.f, t4 = 0.f;
                #pragma unroll
                for (int q = 0; q < 9; ++q) {
                    const float4 v = sws[oh + q][ow];
                    t0 += v.x; t1 += v.y; t2 += v.z; t3 += v.w;
                    t4 += sw4[oh + q][ow];
                }
                run0 += t0 - rbuf[0][jj]; rbuf[0][jj] = t0;
                run1 += t1 - rbuf[1][jj]; rbuf[1][jj] = t1;
                run2 += t2 - rbuf[2][jj]; rbuf[2][jj] = t2;
                run3 += t3 - rbuf[3][jj]; rbuf[3][jj] = t3;
                run4 += t4 - rbuf[4][jj]; rbuf[4][jj] = t4;

                if (s >= 8) {                // window [d-4, d+4] complete
                    const float uI = run0 * inv, uJ = run1 * inv;
                    const float cross = run4 - uI * run1;
                    const float Iv = fmaxf(run2 - uI * run0, 1e-5f);
                    const float Jv = fmaxf(run3 - uJ * run1, 1e-5f);
                    acc += cross * cross / (Iv * Jv + 1e-5f);
                }
            }
        }
    }

    // ---- block reduction, one fp32 atomic per block ----
    #pragma unroll
    for (int off = 32; off > 0; off >>= 1)
        acc += __shfl_down(acc, off, 64);
    if (lane == 0) wred[wid] = acc;
    __syncthreads();
    if (tid == 0)
        atomicAdd(outp, -(wred[0] + wred[1] + wred[2] + wred[3]));
}

extern "C" void kernel_launch(void* const* d_in, const int* in_sizes, int n_in,
                              void* d_out, int out_size, void* d_ws, size_t ws_size,
                              hipStream_t stream)
{
    const float* I = (const float*)d_in[0];   // y_true
    const float* J = (const float*)d_in[1];   // y_pred
    float* out = (float*)d_out;

    hipMemsetAsync(out, 0, sizeof(float), stream);

    dim3 grid(WW / TW, HH / TH, ND * NCH);    // 10 x 12 x 8 = 960 blocks
    ncc_fused<<<grid, 256, 0, stream>>>(I, J, out);
}

// Round 7
// 210.314 us; speedup vs baseline: 1.0411x; 1.0411x over previous
//
#include <hip/hip_runtime.h>

// NCC loss, fused single-kernel, v3.
// Inputs y_true, y_pred: (2,1,160,192,160) FP32. Output: 1 FP32 scalar = -sum(cc).
// R5/R6 diagnosis: LDS-pipe-bound. v3: stage A computes W-sums of the 5 product
// fields directly from global (L1-served aligned dwordx4, no raw->LDS round
// trip), writes float4+float per position; stage B does 9 H-taps (b128+b32)
// from +1-padded LDS (row stride 17 float4 = 68 words = 4 mod 32 -> <=2-way,
// conflict-free); D handled by per-thread 9-slot register ring (R5-verified).
#define ND 2
#define DD 160
#define HH 192
#define WW 160
#define HW (HH * WW)

constexpr int TW    = 16;          // output tile width
constexpr int TH    = 16;          // output tile height
constexpr int HLO   = TH + 8;      // 24 W-sum rows incl. H halo
constexpr int CHUNK = 40;          // output d's per block
constexpr int NCH   = DD / CHUNK;  // 4
constexpr int NSL   = CHUNK + 8;   // 48 slices per block

__global__ __launch_bounds__(256)
void ncc_fused(const float* __restrict__ I, const float* __restrict__ J,
               float* __restrict__ outp)
{
    __shared__ float4 sws[HLO][TW + 1];   // fields (I,J,II,JJ); +1 pad kills conflicts
    __shared__ float  sw4[HLO][TW + 1];   // field IJ
    __shared__ float  wred[4];

    const int tid  = threadIdx.x;
    const int w0   = blockIdx.x * TW;
    const int h0   = blockIdx.y * TH;
    const int z    = blockIdx.z;           // n * NCH + chunk
    const int n    = z / NCH;
    const int d0   = (z % NCH) * CHUNK;
    const int lane = tid & 63, wid = tid >> 6;
    const int oh   = tid >> 4, ow = tid & 15;   // stage-B output pixel

    // stage-A job constants (threads 0..95: row 0..23 x wgroup 0..3)
    const int arow = tid >> 2;
    const int awg  = tid & 3;
    const int agh  = h0 + arow - 4;
    const int agws = w0 + awg * 4 - 4;     // aligned start of 12-float window
    const bool ajob = (tid < 96);
    const bool ahok = (agh >= 0) && (agh < HH);

    float rbuf[5][9];
    #pragma unroll
    for (int p = 0; p < 5; ++p)
        #pragma unroll
        for (int q = 0; q < 9; ++q) rbuf[p][q] = 0.f;
    float run0 = 0.f, run1 = 0.f, run2 = 0.f, run3 = 0.f, run4 = 0.f;
    float acc = 0.f;
    const float inv = 1.0f / 729.0f;

    #pragma unroll 1
    for (int g = 0; g < 6; ++g) {          // 6 x 9 = 54 >= NSL
        #pragma unroll
        for (int jj = 0; jj < 9; ++jj) {
            const int s = g * 9 + jj;      // uniform across block
            if (s < NSL) {
                const int dd = d0 - 4 + s; // slice entering the D window
                float t0 = 0.f, t1 = 0.f, t2 = 0.f, t3 = 0.f, t4 = 0.f;

                if (dd >= 0 && dd < DD) {  // block-uniform branch
                    const int slice = (n * DD + dd) * HW;

                    // ---- stage A: global -> W-sums of 5 fields -> LDS ----
                    if (ajob) {
                        float a[12], b[12];
                        #pragma unroll
                        for (int c = 0; c < 3; ++c) {
                            const int gw = agws + 4 * c;
                            float4 va = make_float4(0.f, 0.f, 0.f, 0.f);
                            float4 vb = va;
                            if (ahok && gw >= 0 && gw < WW) {
                                const int gg = slice + agh * WW + gw;
                                va = *(const float4*)(I + gg);
                                vb = *(const float4*)(J + gg);
                            }
                            *(float4*)&a[4 * c] = va;
                            *(float4*)&b[4 * c] = vb;
                        }
                        float S0[4], S1[4], S2[4], S3[4], S4[4];
                        {   // field I
                            float f0 = a[0]+a[1]+a[2]+a[3]+a[4]+a[5]+a[6]+a[7]+a[8];
                            S0[0] = f0;
                            #pragma unroll
                            for (int t = 1; t < 4; ++t) { f0 += a[t+8] - a[t-1]; S0[t] = f0; }
                        }
                        {   // field J
                            float f0 = b[0]+b[1]+b[2]+b[3]+b[4]+b[5]+b[6]+b[7]+b[8];
                            S1[0] = f0;
                            #pragma unroll
                            for (int t = 1; t < 4; ++t) { f0 += b[t+8] - b[t-1]; S1[t] = f0; }
                        }
                        {   // field I*I
                            float f[12];
                            #pragma unroll
                            for (int i = 0; i < 12; ++i) f[i] = a[i] * a[i];
                            float f0 = f[0]+f[1]+f[2]+f[3]+f[4]+f[5]+f[6]+f[7]+f[8];
                            S2[0] = f0;
                            #pragma unroll
                            for (int t = 1; t < 4; ++t) { f0 += f[t+8] - f[t-1]; S2[t] = f0; }
                        }
                        {   // field J*J
                            float f[12];
                            #pragma unroll
                            for (int i = 0; i < 12; ++i) f[i] = b[i] * b[i];
                            float f0 = f[0]+f[1]+f[2]+f[3]+f[4]+f[5]+f[6]+f[7]+f[8];
                            S3[0] = f0;
                            #pragma unroll
                            for (int t = 1; t < 4; ++t) { f0 += f[t+8] - f[t-1]; S3[t] = f0; }
                        }
                        {   // field I*J
                            float f[12];
                            #pragma unroll
                            for (int i = 0; i < 12; ++i) f[i] = a[i] * b[i];
                            float f0 = f[0]+f[1]+f[2]+f[3]+f[4]+f[5]+f[6]+f[7]+f[8];
                            S4[0] = f0;
                            #pragma unroll
                            for (int t = 1; t < 4; ++t) { f0 += f[t+8] - f[t-1]; S4[t] = f0; }
                        }
                        #pragma unroll
                        for (int t = 0; t < 4; ++t) {
                            sws[arow][awg * 4 + t] = make_float4(S0[t], S1[t], S2[t], S3[t]);
                            sw4[arow][awg * 4 + t] = S4[t];
                        }
                    }
                    __syncthreads();

                    // ---- stage B: 9 H-taps, b128 + b32 ----
                    #pragma unroll
                    for (int q = 0; q < 9; ++q) {
                        const float4 v = sws[oh + q][ow];
                        t0 += v.x; t1 += v.y; t2 += v.z; t3 += v.w;
                        t4 += sw4[oh + q][ow];
                    }
                    __syncthreads();   // protect sws/sw4 before next stage A
                }

                // ---- D-ring update (slot jj static after unroll) ----
                run0 += t0 - rbuf[0][jj]; rbuf[0][jj] = t0;
                run1 += t1 - rbuf[1][jj]; rbuf[1][jj] = t1;
                run2 += t2 - rbuf[2][jj]; rbuf[2][jj] = t2;
                run3 += t3 - rbuf[3][jj]; rbuf[3][jj] = t3;
                run4 += t4 - rbuf[4][jj]; rbuf[4][jj] = t4;

                if (s >= 8) {              // window [d-4, d+4] complete
                    const float uI = run0 * inv, uJ = run1 * inv;
                    const float cross = run4 - uI * run1;
                    const float Iv = fmaxf(run2 - uI * run0, 1e-5f);
                    const float Jv = fmaxf(run3 - uJ * run1, 1e-5f);
                    acc += cross * cross / (Iv * Jv + 1e-5f);
                }
            }
        }
    }

    // ---- block reduction, one fp32 atomic per block ----
    #pragma unroll
    for (int off = 32; off > 0; off >>= 1)
        acc += __shfl_down(acc, off, 64);
    if (lane == 0) wred[wid] = acc;
    __syncthreads();
    if (tid == 0)
        atomicAdd(outp, -(wred[0] + wred[1] + wred[2] + wred[3]));
}

extern "C" void kernel_launch(void* const* d_in, const int* in_sizes, int n_in,
                              void* d_out, int out_size, void* d_ws, size_t ws_size,
                              hipStream_t stream)
{
    const float* I = (const float*)d_in[0];   // y_true
    const float* J = (const float*)d_in[1];   // y_pred
    float* out = (float*)d_out;

    hipMemsetAsync(out, 0, sizeof(float), stream);

    dim3 grid(WW / TW, HH / TH, ND * NCH);    // 10 x 12 x 8 = 960 blocks
    ncc_fused<<<grid, 256, 0, stream>>>(I, J, out);
}